// Round 1
// baseline (9546.688 us; speedup 1.0000x reference)
//
#include <hip/hip_runtime.h>
#include <math.h>

#define BB 16
#define SS 64
#define MM 2048
#define DD 256
#define TOPK 8
#define NB 16
#define ROWS (MM / NB)     // 128
#define SCALE 0.0625f      // 1/sqrt(256)

__device__ __forceinline__ float wave_sum(float p) {
    for (int o = 32; o; o >>= 1) p += __shfl_xor(p, o);
    return p;
}

__device__ __forceinline__ void wave_argmax(float& v, int& i) {
    for (int o = 32; o; o >>= 1) {
        float ov = __shfl_xor(v, o);
        int oi = __shfl_xor(i, o);
        if (ov > v || (ov == v && oi < i)) { v = ov; i = oi; }
    }
}

// q = xt@Wq.T + bq (into qs); qk[b] = q@Wk; c0[b] = q.bk
__device__ void compute_qk_dev(const float* __restrict__ x, int b, int t,
                               const float* __restrict__ Wq, const float* __restrict__ bq,
                               const float* __restrict__ Wk, const float* __restrict__ bk,
                               float* __restrict__ qk, float* __restrict__ c0,
                               float* xs, float* qs, float* red4) {
    const int tid = threadIdx.x, w = tid >> 6, lane = tid & 63;
    xs[tid] = x[((size_t)b * SS + t) * DD + tid];
    __syncthreads();
    float4 x4 = ((const float4*)xs)[lane];
    for (int j = w * 64; j < w * 64 + 64; ++j) {
        float4 wq = ((const float4*)(Wq + (size_t)j * DD))[lane];
        float p = wave_sum(wq.x * x4.x + wq.y * x4.y + wq.z * x4.z + wq.w * x4.w);
        if (lane == 0) qs[j] = p + bq[j];
    }
    __syncthreads();
    float acc = 0.f;
    for (int j = 0; j < DD; ++j) acc = fmaf(qs[j], Wk[(size_t)j * DD + tid], acc);
    qk[b * DD + tid] = acc;
    float pc = wave_sum(qs[tid] * bk[tid]);
    if (lane == 0) red4[w] = pc;
    __syncthreads();
    if (tid == 0) c0[b] = red4[0] + red4[1] + red4[2] + red4[3];
}

__global__ __launch_bounds__(256) void k_bcast(const float* __restrict__ memory,
                                               float* __restrict__ mem) {
    int i = blockIdx.x * blockDim.x + threadIdx.x;   // over M*D/4 float4s
    float4 v = ((const float4*)memory)[i];
    for (int b = 0; b < BB; ++b)
        ((float4*)mem)[(size_t)b * (MM * DD / 4) + i] = v;
}

__global__ __launch_bounds__(256) void k_qk0(const float* __restrict__ x,
                                             const float* __restrict__ Wq, const float* __restrict__ bq,
                                             const float* __restrict__ Wk, const float* __restrict__ bk,
                                             float* __restrict__ qk, float* __restrict__ c0) {
    __shared__ float xs[DD], qs[DD], red4[4];
    compute_qk_dev(x, blockIdx.x, 0, Wq, bq, Wk, bk, qk, c0, xs, qs, red4);
}

// One pass over mem per step: scores, exp, partial denom, partial attn-weighted mem sum.
__global__ __launch_bounds__(256) void k_scores(const float* __restrict__ mem,
                                                const float* __restrict__ qk,
                                                const float* __restrict__ c0,
                                                float* __restrict__ ebuf,
                                                float* __restrict__ pe,
                                                float* __restrict__ pam) {
    const int blk = blockIdx.x, b = blockIdx.y;
    const int tid = threadIdx.x, w = tid >> 6, lane = tid & 63;
    __shared__ float qks[DD];
    __shared__ float peS[4];
    __shared__ float pamS[4][DD];
    qks[tid] = qk[b * DD + tid];
    __syncthreads();
    const float c0v = c0[b];
    float4 qk4 = ((const float4*)qks)[lane];
    const float* memB = mem + ((size_t)b * MM + (size_t)blk * ROWS) * DD;
    float4 acc = make_float4(0.f, 0.f, 0.f, 0.f);
    float peAcc = 0.f;
    for (int r = w; r < ROWS; r += 4) {
        float4 v = ((const float4*)(memB + (size_t)r * DD))[lane];
        float p = wave_sum(v.x * qk4.x + v.y * qk4.y + v.z * qk4.z + v.w * qk4.w);
        float e = expf((p + c0v) * SCALE);
        acc.x += e * v.x; acc.y += e * v.y; acc.z += e * v.z; acc.w += e * v.w;
        peAcc += e;
        if (lane == 0) ebuf[(size_t)b * MM + blk * ROWS + r] = e;
    }
    ((float4*)(pamS[w]))[lane] = acc;
    if (lane == 0) peS[w] = peAcc;
    __syncthreads();
    if (tid == 0) pe[b * NB + blk] = peS[0] + peS[1] + peS[2] + peS[3];
    float s = pamS[0][tid] + pamS[1][tid] + pamS[2][tid] + pamS[3][tid];
    pam[((size_t)b * NB + blk) * DD + tid] = s;
}

// Per-batch: normalize, mem_out, gate, top-8, mem row update, next-step qk.
__global__ __launch_bounds__(256) void k_finalize(
    const float* __restrict__ x,
    const float* __restrict__ Wq, const float* __restrict__ bq,
    const float* __restrict__ Wk, const float* __restrict__ bk,
    const float* __restrict__ Wv, const float* __restrict__ bv,
    const float* __restrict__ Wu, const float* __restrict__ bu,
    float* __restrict__ mem, float* __restrict__ qk, float* __restrict__ c0,
    const float* __restrict__ pe, const float* __restrict__ pam,
    float* __restrict__ ebuf, float* __restrict__ out, int t) {
    const int b = blockIdx.x;
    const int tid = threadIdx.x, w = tid >> 6, lane = tid & 63;
    __shared__ float xs[DD], qs[DD], am[DD], mo[DD], gs[DD];
    __shared__ float ev[MM];
    __shared__ float red4[4];
    __shared__ int redi[4];
    __shared__ float totS;
    __shared__ int idxsS[TOPK];

    if (tid == 0) {
        float s = 0.f;
        for (int i = 0; i < NB; ++i) s += pe[b * NB + i];
        totS = s;
    }
    xs[tid] = x[((size_t)b * SS + t) * DD + tid];
    for (int i = 0; i < MM / 256; ++i)
        ev[tid + i * 256] = ebuf[(size_t)b * MM + tid + i * 256];
    __syncthreads();

    float a = 0.f;
    for (int i = 0; i < NB; ++i) a += pam[((size_t)b * NB + i) * DD + tid];
    am[tid] = a / totS;
    __syncthreads();

    // mem_out = am @ Wv.T + bv
    float4 a4 = ((const float4*)am)[lane];
    for (int j = w * 64; j < w * 64 + 64; ++j) {
        float4 wv = ((const float4*)(Wv + (size_t)j * DD))[lane];
        float p = wave_sum(wv.x * a4.x + wv.y * a4.y + wv.z * a4.z + wv.w * a4.w);
        if (lane == 0) mo[j] = p + bv[j];
    }
    __syncthreads();
    out[((size_t)b * SS + t) * DD + tid] = mo[tid];

    // gate = sigmoid([xt, mem_out] @ Wu.T + bu)
    float4 x4 = ((const float4*)xs)[lane];
    float4 m4 = ((const float4*)mo)[lane];
    for (int j = w * 64; j < w * 64 + 64; ++j) {
        const float* wu = Wu + (size_t)j * (2 * DD);
        float4 wl = ((const float4*)wu)[lane];
        float4 wh = ((const float4*)(wu + DD))[lane];
        float p = wave_sum(wl.x * x4.x + wl.y * x4.y + wl.z * x4.z + wl.w * x4.w +
                           wh.x * m4.x + wh.y * m4.y + wh.z * m4.z + wh.w * m4.w);
        if (lane == 0) gs[j] = 1.f / (1.f + expf(-(p + bu[j])));
    }
    __syncthreads();

    // top-8 via masked argmax (order of e == order of attn)
    for (int k = 0; k < TOPK; ++k) {
        float bv_ = -1e30f; int bi = MM;
        for (int i = 0; i < MM / 256; ++i) {
            int idx = tid + i * 256;
            float v = ev[idx];
            if (v > bv_) { bv_ = v; bi = idx; }
        }
        wave_argmax(bv_, bi);
        if (lane == 0) { red4[w] = bv_; redi[w] = bi; }
        __syncthreads();
        if (tid == 0) {
            float best = red4[0]; int besti = redi[0];
            for (int ww = 1; ww < 4; ++ww)
                if (red4[ww] > best || (red4[ww] == best && redi[ww] < besti)) {
                    best = red4[ww]; besti = redi[ww];
                }
            idxsS[k] = besti;
            ev[besti] = -1e30f;
        }
        __syncthreads();
    }

    // mem row updates (indices distinct)
    {
        float g = gs[tid], xv = xs[tid];
        for (int k = 0; k < TOPK; ++k) {
            int row = idxsS[k];
            size_t off = ((size_t)b * MM + row) * DD + tid;
            mem[off] = (1.f - g) * mem[off] + g * xv;
        }
    }

    // next step's qk
    if (t + 1 < SS) {
        __syncthreads();
        compute_qk_dev(x, b, t + 1, Wq, bq, Wk, bk, qk, c0, xs, qs, red4);
    }
}

extern "C" void kernel_launch(void* const* d_in, const int* in_sizes, int n_in,
                              void* d_out, int out_size, void* d_ws, size_t ws_size,
                              hipStream_t stream) {
    const float* x      = (const float*)d_in[0];
    const float* memory = (const float*)d_in[1];
    const float* Wq     = (const float*)d_in[2];
    const float* bq     = (const float*)d_in[3];
    const float* Wk     = (const float*)d_in[4];
    const float* bk     = (const float*)d_in[5];
    const float* Wv     = (const float*)d_in[6];
    const float* bv     = (const float*)d_in[7];
    const float* Wu     = (const float*)d_in[8];
    const float* bu     = (const float*)d_in[9];
    float* out = (float*)d_out;

    float* ws   = (float*)d_ws;
    float* mem  = ws;                                // B*M*D
    float* qk   = mem + (size_t)BB * MM * DD;        // B*D
    float* c0   = qk + BB * DD;                      // B
    float* pe   = c0 + BB;                           // B*NB
    float* pam  = pe + BB * NB;                      // B*NB*D
    float* ebuf = pam + (size_t)BB * NB * DD;        // B*M

    k_bcast<<<MM * DD / 4 / 256, 256, 0, stream>>>(memory, mem);
    k_qk0<<<BB, 256, 0, stream>>>(x, Wq, bq, Wk, bk, qk, c0);
    for (int t = 0; t < SS; ++t) {
        k_scores<<<dim3(NB, BB), 256, 0, stream>>>(mem, qk, c0, ebuf, pe, pam);
        k_finalize<<<BB, 256, 0, stream>>>(x, Wq, bq, Wk, bk, Wv, bv, Wu, bu,
                                           mem, qk, c0, pe, pam, ebuf, out, t);
    }
}

// Round 2
// 2736.904 us; speedup vs baseline: 3.4881x; 3.4881x over previous
//
#include <hip/hip_runtime.h>
#include <math.h>

#define BB 16
#define SS 64
#define MM 2048
#define DD 256
#define TOPK 8
#define NB 16
#define ROWS (MM / NB)     // 128
#define SCALE 0.0625f      // 1/sqrt(256)

__device__ __forceinline__ float wave_sum(float p) {
    for (int o = 32; o; o >>= 1) p += __shfl_xor(p, o);
    return p;
}

__device__ __forceinline__ void wave_argmax(float& v, int& i) {
    for (int o = 32; o; o >>= 1) {
        float ov = __shfl_xor(v, o);
        int oi = __shfl_xor(i, o);
        if (ov > v || (ov == v && oi < i)) { v = ov; i = oi; }
    }
}

// Broadcast memory to per-batch copies.
__global__ __launch_bounds__(256) void k_bcast(const float* __restrict__ memory,
                                               float* __restrict__ mem) {
    int i = blockIdx.x * blockDim.x + threadIdx.x;   // over M*D/4 float4s
    float4 v = ((const float4*)memory)[i];
    for (int b = 0; b < BB; ++b)
        ((float4*)mem)[(size_t)b * (MM * DD / 4) + i] = v;
}

// WvT[d][j] = Wv[j][d]
__global__ __launch_bounds__(256) void k_transpose(const float* __restrict__ Wv,
                                                   float* __restrict__ WvT) {
    __shared__ float ts[32][33];
    int bx = blockIdx.x & 7, by = blockIdx.x >> 3;      // 8x8 tiles of 32x32
    int x_ = threadIdx.x & 31, y_ = threadIdx.x >> 5;   // 32 x 8
    for (int ky = 0; ky < 4; ++ky)
        ts[y_ + 8 * ky][x_] = Wv[(size_t)(by * 32 + y_ + 8 * ky) * DD + bx * 32 + x_];
    __syncthreads();
    for (int ky = 0; ky < 4; ++ky)
        WvT[(size_t)(bx * 32 + y_ + 8 * ky) * DD + by * 32 + x_] = ts[x_][y_ + 8 * ky];
}

// Precompute for ALL (b,t): qk[b,t] = (x_t @ Wq.T + bq) @ Wk ; c0[b,t] = q . bk
// (independent of mem, so it hoists out of the sequential loop entirely)
__global__ __launch_bounds__(256) void k_qkall(const float* __restrict__ x,
                                               const float* __restrict__ Wq, const float* __restrict__ bq,
                                               const float* __restrict__ Wk, const float* __restrict__ bk,
                                               float* __restrict__ qkAll, float* __restrict__ c0All) {
    const int b = blockIdx.x >> 4, tc = blockIdx.x & 15;
    const int tid = threadIdx.x, w = tid >> 6, lane = tid & 63;
    __shared__ float xs[DD], qs[DD], red4[4];
    for (int i = 0; i < 4; ++i) {
        int t = tc * 4 + i;
        xs[tid] = x[((size_t)b * SS + t) * DD + tid];
        __syncthreads();
        float4 x4 = ((const float4*)xs)[lane];
        for (int j = w * 64; j < w * 64 + 64; ++j) {
            float4 wq = ((const float4*)(Wq + (size_t)j * DD))[lane];
            float p = wave_sum(wq.x * x4.x + wq.y * x4.y + wq.z * x4.z + wq.w * x4.w);
            if (lane == 0) qs[j] = p + bq[j];
        }
        __syncthreads();
        float acc = 0.f;
        for (int jj = 0; jj < DD; ++jj) acc = fmaf(qs[jj], Wk[(size_t)jj * DD + tid], acc);
        qkAll[((size_t)b * SS + t) * DD + tid] = acc;
        float pc = wave_sum(qs[tid] * bk[tid]);
        if (lane == 0) red4[w] = pc;
        __syncthreads();
        if (tid == 0) c0All[b * SS + t] = red4[0] + red4[1] + red4[2] + red4[3];
        __syncthreads();
    }
}

// Per step, pass over mem: scores, exp, partial denom, partial weighted-mem sum,
// plus per-chunk top-8 candidates (global top-8 is contained in chunk top-8s).
__global__ __launch_bounds__(256) void k_scores(const float* __restrict__ mem,
                                                const float* __restrict__ qkAll,
                                                const float* __restrict__ c0All,
                                                float* __restrict__ pe,
                                                float* __restrict__ pam,
                                                float* __restrict__ candV,
                                                int* __restrict__ candI, int t) {
    const int blk = blockIdx.x, b = blockIdx.y;
    const int tid = threadIdx.x, w = tid >> 6, lane = tid & 63;
    __shared__ float qks[DD];
    __shared__ float peS[4];
    __shared__ float pamS[4][DD];
    __shared__ float es[ROWS];
    qks[tid] = qkAll[((size_t)b * SS + t) * DD + tid];
    __syncthreads();
    const float c0v = c0All[b * SS + t];
    float4 qk4 = ((const float4*)qks)[lane];
    const float* memB = mem + ((size_t)b * MM + (size_t)blk * ROWS) * DD;
    float4 acc = make_float4(0.f, 0.f, 0.f, 0.f);
    float peAcc = 0.f;
    for (int r = w; r < ROWS; r += 4) {
        float4 v = ((const float4*)(memB + (size_t)r * DD))[lane];
        float p = wave_sum(v.x * qk4.x + v.y * qk4.y + v.z * qk4.z + v.w * qk4.w);
        float e = expf((p + c0v) * SCALE);
        acc.x += e * v.x; acc.y += e * v.y; acc.z += e * v.z; acc.w += e * v.w;
        peAcc += e;
        if (lane == 0) es[r] = e;
    }
    ((float4*)(pamS[w]))[lane] = acc;
    if (lane == 0) peS[w] = peAcc;
    __syncthreads();
    if (tid == 0) pe[b * NB + blk] = peS[0] + peS[1] + peS[2] + peS[3];
    {
        float s = pamS[0][tid] + pamS[1][tid] + pamS[2][tid] + pamS[3][tid];
        pam[((size_t)b * NB + blk) * DD + tid] = s;
    }
    // wave 0: local top-8 of es[0..127] (register copies, invalidate by index)
    if (w == 0) {
        float v0 = es[lane], v1 = es[lane + 64];
        int i0 = lane, i1 = lane + 64;
        for (int k = 0; k < TOPK; ++k) {
            float bv_ = v0; int bi = i0;
            if (v1 > v0 || (v1 == v0 && i1 < i0)) { bv_ = v1; bi = i1; }
            wave_argmax(bv_, bi);
            if (lane == 0) {
                candV[(b * NB + blk) * TOPK + k] = bv_;
                candI[(b * NB + blk) * TOPK + k] = blk * ROWS + bi;
            }
            if (i0 == bi) v0 = -1e30f;
            if (i1 == bi) v1 = -1e30f;
        }
    }
}

// Per step epilogue, spread over 256 blocks: block (jc, b) computes full mem_out
// (redundantly, coalesced GEMV vs WvT), its 16-wide gate slice, merged top-8,
// and updates its 16 d-columns of the 8 selected mem rows.
__global__ __launch_bounds__(256) void k_fin2(const float* __restrict__ x,
                                              const float* __restrict__ WvT, const float* __restrict__ bv,
                                              const float* __restrict__ Wu, const float* __restrict__ bu,
                                              const float* __restrict__ pe, const float* __restrict__ pam,
                                              const float* __restrict__ candV, const int* __restrict__ candI,
                                              float* __restrict__ mem, float* __restrict__ out, int t) {
    const int jc = blockIdx.x, b = blockIdx.y;
    const int tid = threadIdx.x, w = tid >> 6, lane = tid & 63;
    __shared__ float xs[DD], am[DD], mos[DD];
    __shared__ float peS[16];
    __shared__ float g16[16];
    __shared__ int topI[TOPK];

    xs[tid] = x[((size_t)b * SS + t) * DD + tid];
    if (tid < 16) peS[tid] = pe[b * NB + tid];
    __syncthreads();
    float tot = 0.f;
#pragma unroll
    for (int i = 0; i < 16; ++i) tot += peS[i];
    float a = 0.f;
#pragma unroll
    for (int p = 0; p < 16; ++p) a += pam[((size_t)b * NB + p) * DD + tid];
    am[tid] = a / tot;
    __syncthreads();

    // mem_out = am @ Wv.T + bv   (thread-per-output, coalesced over WvT rows)
    float macc = bv[tid];
    for (int d = 0; d < DD; ++d) macc = fmaf(am[d], WvT[(size_t)d * DD + tid], macc);
    mos[tid] = macc;
    if (jc == 0) out[((size_t)b * SS + t) * DD + tid] = macc;
    __syncthreads();

    // gate slice: j in [jc*16, jc*16+16), 4 j per wave
    float4 x4 = ((const float4*)xs)[lane];
    float4 m4 = ((const float4*)mos)[lane];
    for (int i = 0; i < 4; ++i) {
        int j = jc * 16 + w * 4 + i;
        const float* wu = Wu + (size_t)j * (2 * DD);
        float4 wl = ((const float4*)wu)[lane];
        float4 wh = ((const float4*)(wu + DD))[lane];
        float p = wave_sum(wl.x * x4.x + wl.y * x4.y + wl.z * x4.z + wl.w * x4.w +
                           wh.x * m4.x + wh.y * m4.y + wh.z * m4.z + wh.w * m4.w);
        if (lane == 0) g16[w * 4 + i] = 1.f / (1.f + expf(-(p + bu[j])));
    }

    // merge 128 candidates -> global top-8 (wave 0, in-register)
    if (w == 0) {
        float v0 = candV[b * NB * TOPK + lane], v1 = candV[b * NB * TOPK + 64 + lane];
        int i0 = candI[b * NB * TOPK + lane], i1 = candI[b * NB * TOPK + 64 + lane];
        for (int k = 0; k < TOPK; ++k) {
            float bv_ = v0; int bi = i0;
            if (v1 > v0 || (v1 == v0 && i1 < i0)) { bv_ = v1; bi = i1; }
            wave_argmax(bv_, bi);
            if (lane == 0) topI[k] = bi;
            if (i0 == bi) v0 = -1e30f;
            if (i1 == bi) v1 = -1e30f;
        }
    }
    __syncthreads();

    // update 8 rows x this block's 16 d-columns (indices distinct per b)
    if (tid < 128) {
        int k = tid >> 4, c = tid & 15;
        int row = topI[k];
        int d = jc * 16 + c;
        float g = g16[c], xv = xs[d];
        size_t off = ((size_t)b * MM + row) * DD + d;
        mem[off] = (1.f - g) * mem[off] + g * xv;
    }
}

extern "C" void kernel_launch(void* const* d_in, const int* in_sizes, int n_in,
                              void* d_out, int out_size, void* d_ws, size_t ws_size,
                              hipStream_t stream) {
    const float* x      = (const float*)d_in[0];
    const float* memory = (const float*)d_in[1];
    const float* Wq     = (const float*)d_in[2];
    const float* bq     = (const float*)d_in[3];
    const float* Wk     = (const float*)d_in[4];
    const float* bk     = (const float*)d_in[5];
    const float* Wv     = (const float*)d_in[6];
    const float* bv     = (const float*)d_in[7];
    const float* Wu     = (const float*)d_in[8];
    const float* bu     = (const float*)d_in[9];
    float* out = (float*)d_out;

    float* ws    = (float*)d_ws;
    float* mem   = ws;                                 // B*M*D
    float* qkAll = mem + (size_t)BB * MM * DD;         // B*S*D
    float* c0All = qkAll + (size_t)BB * SS * DD;       // B*S
    float* pe    = c0All + BB * SS;                    // B*NB
    float* pam   = pe + BB * NB;                       // B*NB*D
    float* candV = pam + (size_t)BB * NB * DD;         // B*NB*TOPK
    int*   candI = (int*)(candV + BB * NB * TOPK);     // B*NB*TOPK
    float* WvT   = (float*)(candI + BB * NB * TOPK);   // D*D

    k_bcast<<<MM * DD / 4 / 256, 256, 0, stream>>>(memory, mem);
    k_transpose<<<64, 256, 0, stream>>>(Wv, WvT);
    k_qkall<<<256, 256, 0, stream>>>(x, Wq, bq, Wk, bk, qkAll, c0All);
    for (int t = 0; t < SS; ++t) {
        k_scores<<<dim3(NB, BB), 256, 0, stream>>>(mem, qkAll, c0All, pe, pam, candV, candI, t);
        k_fin2<<<dim3(NB, BB), 256, 0, stream>>>(x, WvT, bv, Wu, bu, pe, pam, candV, candI, mem, out, t);
    }
}